// Round 16
// baseline (362.690 us; speedup 1.0000x reference)
//
#include <hip/hip_runtime.h>

// ---------------- problem constants ----------------
constexpr int Nn   = 100000;   // nodes
constexpr int Ee   = 1600000;  // edges
constexpr int D    = 128;      // hidden = input dim
constexpr int DOUT = 40;       // classifier out
constexpr int DCAT = 384;      // 3*D concat width
constexpr int CPAD = 48;       // DOUT padded to 3x16 MFMA col tiles
constexpr int WS   = 392;      // Wct row stride (halfs)

// CSR layout parameters
constexpr int BINSH  = 8;                          // 256 nodes per bin
constexpr int BINSZ  = 1 << BINSH;
constexpr int BINS   = (Nn + BINSZ - 1) / BINSZ;   // 391
constexpr int SEGCAP = 5376;                       // max edges/bin (mean 4092, +20 sigma)
constexpr int PADCAP = SEGCAP + 7 * BINSZ;         // 7168: per-bin padded CSR stride

typedef _Float16 f16;
typedef _Float16 f16x2 __attribute__((ext_vector_type(2)));
typedef _Float16 f16x4 __attribute__((ext_vector_type(4)));
typedef _Float16 f16x8 __attribute__((ext_vector_type(8)));
typedef float    f32x2 __attribute__((ext_vector_type(2)));
typedef float    f32x4 __attribute__((ext_vector_type(4)));
typedef int      i32x4 __attribute__((ext_vector_type(4)));

// ---------------- edge dtype detect (inlined per block; no extra launch) ----------------
__device__ inline int detect_flag(const int* __restrict__ ei) {
    unsigned orv = 0;
#pragma unroll
    for (int j = 1; j < 16; j += 2) orv |= (unsigned)ei[j];
    return orv == 0u;  // 1 => int64 layout
}

__device__ inline void load_edge(const int* __restrict__ ei, int f, int e, int& s, int& d) {
    if (f) {  // int64: read 8B, use low word
        s = ((const int2*)ei)[e].x;
        d = ((const int2*)ei)[Ee + e].x;
    } else {
        s = ei[e];
        d = ei[Ee + e];
    }
}

// ---------------- S1: degree count (d-half only) ----------------
__global__ __launch_bounds__(256) void deg_count(const int* __restrict__ ei,
                                                 int* __restrict__ deg) {
    int f = detect_flag(ei);
    for (int e = blockIdx.x * 256 + threadIdx.x; e < Ee; e += gridDim.x * 256) {
        int d = f ? ((const int2*)ei)[Ee + e].x : ei[Ee + e];
        if ((unsigned)d < (unsigned)Nn) atomicAdd(&deg[d], 1);
    }
}

// ---------------- S2: per-bin scan -> rowBase, dinv, rec-meta, pad sentinels ----------------
__global__ __launch_bounds__(256) void node_scan(const int* __restrict__ deg,
                                                 int* __restrict__ rowBase,
                                                 float* __restrict__ dinv,
                                                 i32x4* __restrict__ rec,
                                                 int* __restrict__ sortedSrc) {
    __shared__ int a[256], b2[256];
    const int t = threadIdx.x;
    const int b = blockIdx.x;
    const int node = b * BINSZ + t;
    int c = (node < Nn) ? deg[node] : 0;
    int pc = (c + 7) & ~7;
    int* pa = a;
    int* pb = b2;
    pa[t] = pc;
    __syncthreads();
    for (int off = 1; off < 256; off <<= 1) {
        int v = pa[t] + ((t >= off) ? pa[t - off] : 0);
        __syncthreads();
        pb[t] = v;
        __syncthreads();
        int* tmp = pa; pa = pb; pb = tmp;
    }
    int base = b * PADCAP + pa[t] - pc;  // exclusive prefix
    if (node < Nn) {
        rowBase[node] = base;
        float dv = rsqrtf((float)(c + 1));  // +1 self loop
        dinv[node] = dv;
        i32x4 r2;
        r2[0] = base;
        r2[1] = c;
        r2[2] = __float_as_int(dv);
        r2[3] = 0;
        rec[(size_t)node * 3 + 2] = r2;
        for (int j = c; j < pc; ++j) sortedSrc[base + j] = Nn;  // pad sentinels (<=7)
    }
}

// ---------------- S3: place edges via slot reservation ----------------
__global__ __launch_bounds__(256) void place(const int* __restrict__ ei,
                                             const int* __restrict__ rowBase,
                                             int* __restrict__ fill,
                                             int* __restrict__ sortedSrc) {
    int f = detect_flag(ei);
    for (int e = blockIdx.x * 256 + threadIdx.x; e < Ee; e += gridDim.x * 256) {
        int s, d;
        load_edge(ei, f, e, s, d);
        if ((unsigned)d < (unsigned)Nn) {
            int ss = ((unsigned)s < (unsigned)Nn) ? s : Nn;  // bad src -> zero row
            int slot = atomicAdd(&fill[d], 1);
            sortedSrc[rowBase[d] + slot] = ss;
        }
    }
}

// ---------------- S4: build rec first-8 (post-place) ----------------
__global__ __launch_bounds__(256) void rec_build(const int* __restrict__ rowBase,
                                                 const int* __restrict__ deg,
                                                 int* __restrict__ sortedSrc,
                                                 i32x4* __restrict__ rec) {
    int node = blockIdx.x * 256 + threadIdx.x;
    if (node >= Nn) return;
    int base = rowBase[node];
    int pc = (deg[node] + 7) & ~7;
    i32x4 r0, r1;
#pragma unroll
    for (int j = 0; j < 4; ++j) r0[j] = (j < pc) ? sortedSrc[base + j] : Nn;
#pragma unroll
    for (int j = 0; j < 4; ++j) r1[j] = (4 + j < pc) ? sortedSrc[base + 4 + j] : Nn;
    rec[(size_t)node * 3 + 0] = r0;
    rec[(size_t)node * 3 + 1] = r1;
}

// ---------------- merged prep ----------------
// blocks 0-2: conv-W transposes; block 3: Wct + fp8 tmp sentinel row.
__global__ __launch_bounds__(256) void prep_all(const float* __restrict__ W0,
                                                const float* __restrict__ W1,
                                                const float* __restrict__ W2,
                                                const float* __restrict__ Wc,
                                                f16* __restrict__ WtAll,
                                                f16* __restrict__ Wct,
                                                unsigned char* __restrict__ tmp8) {
    int b = blockIdx.x;
    if (b < 3) {
        const float* W = (b == 0) ? W0 : ((b == 1) ? W1 : W2);
        f16* Wt = WtAll + (size_t)b * D * D;
        for (int i = threadIdx.x; i < D * D; i += 256) {
            int k = i >> 7, c = i & 127;
            Wt[c * D + k] = (f16)W[i];
        }
    } else {
        if (threadIdx.x < 32)  // fp8 sentinel zero row (128 B)
            ((unsigned*)(tmp8 + (size_t)Nn * 128))[threadIdx.x] = 0u;
        for (int i = threadIdx.x; i < CPAD * WS; i += 256) {
            int c = i / WS, k = i - c * WS;
            f16 v = (f16)0.0f;
            if (c < DOUT && k < DCAT) v = (f16)Wc[k * DOUT + c];
            Wct[i] = v;
        }
    }
}

// ---------------- fused embed+conv1 GEMM ----------------
// h0 = relu(x @ We^T + b_e) -> hcat part0 AND LDS (swizzled);
// tmp8 = fp8_e4m3( (h0 @ W1^T) * dinv ). Saves the 25.6 MB h0 re-read.
__global__ __launch_bounds__(256) void gemm_fused01(const float* __restrict__ x,
                                                    const f16* __restrict__ WeT,
                                                    const f16* __restrict__ W1T,
                                                    const float* __restrict__ b_embed,
                                                    const float* __restrict__ dinv,
                                                    f16* __restrict__ hcat,
                                                    unsigned char* __restrict__ tmp8) {
    __shared__ f16 Bsw[128 * 128];  // 32 KB (We^T, then W1^T)
    __shared__ f16 Hsw[128 * 128];  // 32 KB h0 tile
    const int tid = threadIdx.x;
    const int r0 = blockIdx.x * 128;
    const int lane = tid & 63;
    const int w = tid >> 6;
    const int wr = w * 32;

    {   // stage We^T
        int row = tid >> 1, half = (tid & 1) * 128;
#pragma unroll
        for (int i = 0; i < 8; ++i) {
            int bir = half + i * 16;
            uint4 v = *(const uint4*)((const char*)WeT + (size_t)row * 256 + bir);
            *(uint4*)((char*)Bsw + row * 256 + (bir ^ ((row & 7) << 4))) = v;
        }
    }
    __syncthreads();

    f32x4 acc[2][8];
#pragma unroll
    for (int mf = 0; mf < 2; ++mf)
#pragma unroll
        for (int nf = 0; nf < 8; ++nf) acc[mf][nf] = (f32x4){0, 0, 0, 0};

    // ---- GEMM0: A = x (fp32, direct from global) ----
#pragma unroll
    for (int kk = 0; kk < 4; ++kk) {
        const int ke = kk * 32 + (lane >> 4) * 8;
        f16x8 a[2], b[8];
#pragma unroll
        for (int mf = 0; mf < 2; ++mf) {
            int row = r0 + wr + mf * 16 + (lane & 15);
            int rc = (row < Nn) ? row : (Nn - 1);
            const float* p = x + (size_t)rc * D + ke;
            float4 f0 = *(const float4*)p;
            float4 f1 = *(const float4*)(p + 4);
            f16x8 h;
            h[0] = (f16)f0.x; h[1] = (f16)f0.y; h[2] = (f16)f0.z; h[3] = (f16)f0.w;
            h[4] = (f16)f1.x; h[5] = (f16)f1.y; h[6] = (f16)f1.z; h[7] = (f16)f1.w;
            a[mf] = h;
        }
#pragma unroll
        for (int nf = 0; nf < 8; ++nf) {
            int col = nf * 16 + (lane & 15);
            int bir = kk * 64 + (lane >> 4) * 16;
            b[nf] = *(const f16x8*)((const char*)Bsw + col * 256 + (bir ^ ((col & 7) << 4)));
        }
#pragma unroll
        for (int mf = 0; mf < 2; ++mf)
#pragma unroll
            for (int nf = 0; nf < 8; ++nf)
                acc[mf][nf] = __builtin_amdgcn_mfma_f32_16x16x32_f16(a[mf], b[nf], acc[mf][nf], 0, 0, 0);
    }

    // ---- epilogue0: bias+relu -> hcat part0 + Hsw (swizzled) ----
    {
        float bv[8];
#pragma unroll
        for (int nf = 0; nf < 8; ++nf) bv[nf] = b_embed[nf * 16 + (lane & 15)];
#pragma unroll
        for (int mf = 0; mf < 2; ++mf) {
#pragma unroll
            for (int i = 0; i < 4; ++i) {
                int lrow = wr + mf * 16 + (lane >> 4) * 4 + i;
                int row = r0 + lrow;
#pragma unroll
                for (int nf = 0; nf < 8; ++nf) {
                    float v = acc[mf][nf][i] + bv[nf];
                    if (v < 0.0f) v = 0.0f;
                    f16 hv = (f16)v;
                    if (row < Nn) hcat[(size_t)row * DCAT + nf * 16 + (lane & 15)] = hv;
                    int bir = (nf * 16 + (lane & 15)) * 2;
                    *(f16*)((char*)Hsw + lrow * 256 + (bir ^ ((lrow & 7) << 4))) = hv;
                }
            }
        }
    }
    __syncthreads();

    {   // restage W1^T
        int row = tid >> 1, half = (tid & 1) * 128;
#pragma unroll
        for (int i = 0; i < 8; ++i) {
            int bir = half + i * 16;
            uint4 v = *(const uint4*)((const char*)W1T + (size_t)row * 256 + bir);
            *(uint4*)((char*)Bsw + row * 256 + (bir ^ ((row & 7) << 4))) = v;
        }
    }
#pragma unroll
    for (int mf = 0; mf < 2; ++mf)
#pragma unroll
        for (int nf = 0; nf < 8; ++nf) acc[mf][nf] = (f32x4){0, 0, 0, 0};
    __syncthreads();

    // ---- GEMM1: A = h0 tile from Hsw ----
#pragma unroll
    for (int kk = 0; kk < 4; ++kk) {
        f16x8 a[2], b[8];
#pragma unroll
        for (int mf = 0; mf < 2; ++mf) {
            int lrow = wr + mf * 16 + (lane & 15);
            int bir = kk * 64 + (lane >> 4) * 16;
            a[mf] = *(const f16x8*)((const char*)Hsw + lrow * 256 + (bir ^ ((lrow & 7) << 4)));
        }
#pragma unroll
        for (int nf = 0; nf < 8; ++nf) {
            int col = nf * 16 + (lane & 15);
            int bir = kk * 64 + (lane >> 4) * 16;
            b[nf] = *(const f16x8*)((const char*)Bsw + col * 256 + (bir ^ ((col & 7) << 4)));
        }
#pragma unroll
        for (int mf = 0; mf < 2; ++mf)
#pragma unroll
            for (int nf = 0; nf < 8; ++nf)
                acc[mf][nf] = __builtin_amdgcn_mfma_f32_16x16x32_f16(a[mf], b[nf], acc[mf][nf], 0, 0, 0);
    }

    // ---- epilogue1: tmp8 = fp8(acc * dinv) ----
#pragma unroll
    for (int mf = 0; mf < 2; ++mf) {
#pragma unroll
        for (int i = 0; i < 4; ++i) {
            int row = r0 + wr + mf * 16 + (lane >> 4) * 4 + i;
            if (row < Nn) {
                float sc = dinv[row];
#pragma unroll
                for (int nf = 0; nf < 8; ++nf) {
                    float v = acc[mf][nf][i] * sc;
                    unsigned pk = __builtin_amdgcn_cvt_pk_fp8_f32(v, v, 0, false);
                    tmp8[(size_t)row * 128 + nf * 16 + (lane & 15)] = (unsigned char)pk;
                }
            }
        }
    }
}

// ---------------- MFMA GEMM (conv2): tmp8 = fp8((A @ Wt^T) * dinv) ----------------
__global__ __launch_bounds__(256) void gemm_mfma(const f16* __restrict__ Ain, int sA,
                                                 const f16* __restrict__ Wt,
                                                 const float* __restrict__ scale,
                                                 unsigned char* __restrict__ tmp8,
                                                 int M) {
    __shared__ f16 Bsw[128 * 128];  // 32 KB
    const int tid = threadIdx.x;
    const int r0 = blockIdx.x * 128;

    {   // stage B
        int row = tid >> 1, half = (tid & 1) * 128;
#pragma unroll
        for (int i = 0; i < 8; ++i) {
            int bir = half + i * 16;
            uint4 v = *(const uint4*)((const char*)Wt + (size_t)row * 256 + bir);
            *(uint4*)((char*)Bsw + row * 256 + (bir ^ ((row & 7) << 4))) = v;
        }
    }
    __syncthreads();

    const int lane = tid & 63;
    const int w    = tid >> 6;
    const int wr   = w * 32;

    f32x4 acc[2][8];
#pragma unroll
    for (int mf = 0; mf < 2; ++mf)
#pragma unroll
        for (int nf = 0; nf < 8; ++nf) acc[mf][nf] = (f32x4){0, 0, 0, 0};

#pragma unroll
    for (int kk = 0; kk < 4; ++kk) {
        const int ke = kk * 32 + (lane >> 4) * 8;
        f16x8 a[2], b[8];
#pragma unroll
        for (int mf = 0; mf < 2; ++mf) {
            int row = r0 + wr + mf * 16 + (lane & 15);
            int rc = (row < M) ? row : (M - 1);
            a[mf] = *(const f16x8*)(Ain + (size_t)rc * sA + ke);
        }
#pragma unroll
        for (int nf = 0; nf < 8; ++nf) {
            int col = nf * 16 + (lane & 15);
            int bir = kk * 64 + (lane >> 4) * 16;
            b[nf] = *(const f16x8*)((const char*)Bsw + col * 256 + (bir ^ ((col & 7) << 4)));
        }
#pragma unroll
        for (int mf = 0; mf < 2; ++mf)
#pragma unroll
            for (int nf = 0; nf < 8; ++nf)
                acc[mf][nf] = __builtin_amdgcn_mfma_f32_16x16x32_f16(a[mf], b[nf], acc[mf][nf], 0, 0, 0);
    }

#pragma unroll
    for (int mf = 0; mf < 2; ++mf) {
#pragma unroll
        for (int i = 0; i < 4; ++i) {
            int row = r0 + wr + mf * 16 + (lane >> 4) * 4 + i;
            if (row < M) {
                float sc = scale[row];
#pragma unroll
                for (int nf = 0; nf < 8; ++nf) {
                    float v = acc[mf][nf][i] * sc;
                    unsigned pk = __builtin_amdgcn_cvt_pk_fp8_f32(v, v, 0, false);
                    tmp8[(size_t)row * 128 + nf * 16 + (lane & 15)] = (unsigned char)pk;
                }
            }
        }
    }
}

// ---------------- aggregation: fp8 rows, dword/lane, record-fed first iteration ----------------
__global__ __launch_bounds__(256) void aggregate_pad(const unsigned char* __restrict__ tmp8,
                                                     const i32x4* __restrict__ rec,
                                                     const int* __restrict__ sortedSrc,
                                                     const float* __restrict__ bias,
                                                     f16* __restrict__ hcat, int partOff) {
    int node = (blockIdx.x * 256 + threadIdx.x) >> 6;  // one wave per node
    int lane = threadIdx.x & 63;
    int l32  = lane & 31;   // dword index within row (features 4*l32..4*l32+3)
    int h    = lane >> 5;   // half-wave: edge-slot group
    if (node >= Nn) return;
    const unsigned* t4 = (const unsigned*)tmp8;  // row = 32 dwords (128 fp8)

    i32x4 rI = rec[(size_t)node * 3 + h];   // this half's first-4 indices
    i32x4 rM = rec[(size_t)node * 3 + 2];   // {basePad, deg, dinv_bits, 0}
    unsigned sv = t4[(size_t)node * 32 + l32];  // self (issues in parallel)

    int base = rM[0];
    int pc = (rM[1] + 7) & ~7;
    float di = __int_as_float(rM[2]);

    f32x2 aLo = (f32x2){0.0f, 0.0f};
    f32x2 aHi = (f32x2){0.0f, 0.0f};
    if (h == 0) {  // self loop counted once
        aLo = __builtin_amdgcn_cvt_pk_f32_fp8((int)sv, false);
        aHi = __builtin_amdgcn_cvt_pk_f32_fp8((int)sv, true);
    }

    {   // iter 1: gathers straight from the record (no idx-load dependency)
        unsigned g0 = t4[(size_t)rI[0] * 32 + l32];
        unsigned g1 = t4[(size_t)rI[1] * 32 + l32];
        unsigned g2 = t4[(size_t)rI[2] * 32 + l32];
        unsigned g3 = t4[(size_t)rI[3] * 32 + l32];
        aLo += __builtin_amdgcn_cvt_pk_f32_fp8((int)g0, false);
        aHi += __builtin_amdgcn_cvt_pk_f32_fp8((int)g0, true);
        aLo += __builtin_amdgcn_cvt_pk_f32_fp8((int)g1, false);
        aHi += __builtin_amdgcn_cvt_pk_f32_fp8((int)g1, true);
        aLo += __builtin_amdgcn_cvt_pk_f32_fp8((int)g2, false);
        aHi += __builtin_amdgcn_cvt_pk_f32_fp8((int)g2, true);
        aLo += __builtin_amdgcn_cvt_pk_f32_fp8((int)g3, false);
        aHi += __builtin_amdgcn_cvt_pk_f32_fp8((int)g3, true);
    }

    for (int e = 8; e < pc; e += 8) {
        i32x4 idx = *(const i32x4*)(sortedSrc + base + e + h * 4);
        unsigned g0 = t4[(size_t)idx[0] * 32 + l32];
        unsigned g1 = t4[(size_t)idx[1] * 32 + l32];
        unsigned g2 = t4[(size_t)idx[2] * 32 + l32];
        unsigned g3 = t4[(size_t)idx[3] * 32 + l32];
        aLo += __builtin_amdgcn_cvt_pk_f32_fp8((int)g0, false);
        aHi += __builtin_amdgcn_cvt_pk_f32_fp8((int)g0, true);
        aLo += __builtin_amdgcn_cvt_pk_f32_fp8((int)g1, false);
        aHi += __builtin_amdgcn_cvt_pk_f32_fp8((int)g1, true);
        aLo += __builtin_amdgcn_cvt_pk_f32_fp8((int)g2, false);
        aHi += __builtin_amdgcn_cvt_pk_f32_fp8((int)g2, true);
        aLo += __builtin_amdgcn_cvt_pk_f32_fp8((int)g3, false);
        aHi += __builtin_amdgcn_cvt_pk_f32_fp8((int)g3, true);
    }

    // cross-half reduce (features identical across halves)
    aLo[0] += __shfl_xor(aLo[0], 32);
    aLo[1] += __shfl_xor(aLo[1], 32);
    aHi[0] += __shfl_xor(aHi[0], 32);
    aHi[1] += __shfl_xor(aHi[1], 32);

    if (h == 0) {
        float4 bb = *(const float4*)(bias + l32 * 4);
        float o0 = di * aLo[0] + bb.x;
        float o1 = di * aLo[1] + bb.y;
        float o2 = di * aHi[0] + bb.z;
        float o3 = di * aHi[1] + bb.w;
        if (o0 < 0.0f) o0 = 0.0f;
        if (o1 < 0.0f) o1 = 0.0f;
        if (o2 < 0.0f) o2 = 0.0f;
        if (o3 < 0.0f) o3 = 0.0f;
        f16x4 o;
        o[0] = (f16)o0; o[1] = (f16)o1; o[2] = (f16)o2; o[3] = (f16)o3;
        *(f16x4*)(hcat + (size_t)node * DCAT + partOff + l32 * 4) = o;
    }
}

// ---------------- MFMA classifier: out[N,40] = hcat[N,384] @ Wct^T + b ----------------
__global__ __launch_bounds__(256) void cls_mfma(const f16* __restrict__ hcat,
                                                const f16* __restrict__ Wct,
                                                const float* __restrict__ bc,
                                                float* __restrict__ out) {
    __shared__ f16 Bs[CPAD * WS];  // 37.6 KB
    const int tid = threadIdx.x;
    for (int i = tid; i < CPAD * WS / 8; i += 256)
        ((uint4*)Bs)[i] = ((const uint4*)Wct)[i];
    __syncthreads();

    const int lane = tid & 63;
    const int w    = tid >> 6;
    const int r0   = blockIdx.x * 128 + w * 32;

    f32x4 acc[2][3];
#pragma unroll
    for (int mf = 0; mf < 2; ++mf)
#pragma unroll
        for (int nf = 0; nf < 3; ++nf) acc[mf][nf] = (f32x4){0, 0, 0, 0};

#pragma unroll 3
    for (int kk = 0; kk < 12; ++kk) {
        const int ke = kk * 32 + (lane >> 4) * 8;
        f16x8 a[2], b[3];
#pragma unroll
        for (int mf = 0; mf < 2; ++mf) {
            int row = r0 + mf * 16 + (lane & 15);
            int rc = (row < Nn) ? row : (Nn - 1);
            a[mf] = *(const f16x8*)(hcat + (size_t)rc * DCAT + ke);
        }
#pragma unroll
        for (int nf = 0; nf < 3; ++nf) {
            int col = nf * 16 + (lane & 15);
            b[nf] = *(const f16x8*)(Bs + col * WS + ke);
        }
#pragma unroll
        for (int mf = 0; mf < 2; ++mf)
#pragma unroll
            for (int nf = 0; nf < 3; ++nf)
                acc[mf][nf] = __builtin_amdgcn_mfma_f32_16x16x32_f16(a[mf], b[nf], acc[mf][nf], 0, 0, 0);
    }

    float bv[3];
#pragma unroll
    for (int nf = 0; nf < 3; ++nf) {
        int col = nf * 16 + (lane & 15);
        bv[nf] = (col < DOUT) ? bc[col] : 0.0f;
    }
#pragma unroll
    for (int mf = 0; mf < 2; ++mf) {
#pragma unroll
        for (int i = 0; i < 4; ++i) {
            int row = r0 + mf * 16 + (lane >> 4) * 4 + i;
            if (row < Nn) {
#pragma unroll
                for (int nf = 0; nf < 3; ++nf) {
                    int col = nf * 16 + (lane & 15);
                    if (col < DOUT) out[(size_t)row * DOUT + col] = acc[mf][nf][i] + bv[nf];
                }
            }
        }
    }
}

// ---------------- launch ----------------
extern "C" void kernel_launch(void* const* d_in, const int* in_sizes, int n_in,
                              void* d_out, int out_size, void* d_ws, size_t ws_size,
                              hipStream_t stream) {
    const float* x       = (const float*)d_in[0];
    const int*   ei      = (const int*)d_in[1];
    const float* W_embed = (const float*)d_in[2];
    const float* b_embed = (const float*)d_in[3];
    const float* W_conv1 = (const float*)d_in[4];
    const float* b_conv1 = (const float*)d_in[5];
    const float* W_conv2 = (const float*)d_in[6];
    const float* b_conv2 = (const float*)d_in[7];
    const float* W_cls   = (const float*)d_in[8];
    const float* b_cls   = (const float*)d_in[9];
    float* out = (float*)d_out;

    char* p = (char*)d_ws;
    size_t o = 0;
    auto carve = [&](size_t bytes) {
        char* r = p + o;
        o = (o + bytes + 255) & ~(size_t)255;
        return r;
    };
    int*      deg       = (int*)carve((size_t)2 * Nn * 4);  // deg[0..Nn) + fill[Nn..2Nn): ONE carve
    int*      fill      = deg + Nn;                          // contiguous -> single memset covers both
    int*      rowBase   = (int*)carve((size_t)Nn * 4);
    int*      sortedSrc = (int*)carve(((size_t)BINS * PADCAP + 1024) * 4);  // 11.2 MB
    i32x4*    rec       = (i32x4*)carve((size_t)Nn * 48);                   // 4.8 MB
    float*    dinv      = (float*)carve((size_t)Nn * 4);
    f16*      WtAll     = (f16*)carve((size_t)3 * D * D * 2);
    f16*      Wct       = (f16*)carve((size_t)CPAD * WS * 2);
    f16*      hcat      = (f16*)carve((size_t)Nn * DCAT * 2);          // 76.8 MB
    unsigned char* tmp8 = (unsigned char*)carve((size_t)(Nn + 1) * 128);  // 12.8 MB fp8 (+sentinel)
    (void)ws_size;

    hipMemsetAsync(deg, 0, (size_t)2 * Nn * 4, stream);  // zeroes deg AND fill exactly
    deg_count<<<1024, 256, 0, stream>>>(ei, deg);
    node_scan<<<BINS, 256, 0, stream>>>(deg, rowBase, dinv, rec, sortedSrc);
    place<<<2048, 256, 0, stream>>>(ei, rowBase, fill, sortedSrc);
    rec_build<<<(Nn + 255) / 256, 256, 0, stream>>>(rowBase, deg, sortedSrc, rec);
    prep_all<<<4, 256, 0, stream>>>(W_embed, W_conv1, W_conv2, W_cls, WtAll, Wct, tmp8);

    const int gGemm = (Nn + 127) / 128;
    const int gAgg  = (Nn * 64) / 256;

    // embed + conv1-GEMM fused: hcat part0 + tmp8 (fp8, *dinv)
    gemm_fused01<<<gGemm, 256, 0, stream>>>(x, WtAll, WtAll + D * D, b_embed, dinv, hcat, tmp8);
    // conv1 aggregate -> hcat part1
    aggregate_pad<<<gAgg, 256, 0, stream>>>(tmp8, rec, sortedSrc, b_conv1, hcat, D);
    // conv2: tmp8 = fp8((h1 @ W2)*dinv), aggregate -> hcat part2
    gemm_mfma<<<gGemm, 256, 0, stream>>>(hcat + D, DCAT, WtAll + 2 * D * D, dinv, tmp8, Nn);
    aggregate_pad<<<gAgg, 256, 0, stream>>>(tmp8, rec, sortedSrc, b_conv2, hcat, 2 * D);
    // classifier
    cls_mfma<<<gGemm, 256, 0, stream>>>(hcat, Wct, b_cls, out);
}

// Round 17
// 236.705 us; speedup vs baseline: 1.5322x; 1.5322x over previous
//
#include <hip/hip_runtime.h>

// ---------------- problem constants ----------------
constexpr int Nn   = 100000;   // nodes
constexpr int Ee   = 1600000;  // edges
constexpr int D    = 128;      // hidden = input dim
constexpr int DOUT = 40;       // classifier out
constexpr int DCAT = 384;      // 3*D concat width
constexpr int CPAD = 48;       // DOUT padded to 3x16 MFMA col tiles
constexpr int WS   = 392;      // Wct row stride (halfs)

// binned-sort parameters
constexpr int BINSH  = 8;                          // 256 nodes per bin
constexpr int BINSZ  = 1 << BINSH;
constexpr int BINS   = (Nn + BINSZ - 1) / BINSZ;   // 391
constexpr int CHUNK  = 8192;                       // edges per scatter block
constexpr int NCHUNK = (Ee + CHUNK - 1) / CHUNK;   // 196
constexpr int SEGCAP = 5376;                       // max edges/bin (mean 4092, +20 sigma)
constexpr int PADCAP = SEGCAP + 7 * BINSZ;         // 7168: per-bin padded CSR stride

typedef _Float16 f16;
typedef _Float16 f16x2 __attribute__((ext_vector_type(2)));
typedef _Float16 f16x4 __attribute__((ext_vector_type(4)));
typedef _Float16 f16x8 __attribute__((ext_vector_type(8)));
typedef float    f32x2 __attribute__((ext_vector_type(2)));
typedef float    f32x4 __attribute__((ext_vector_type(4)));
typedef int      i32x4 __attribute__((ext_vector_type(4)));

// ---------------- edge dtype detect (inlined per block; no extra launch) ----------------
__device__ inline int detect_flag(const int* __restrict__ ei) {
    unsigned orv = 0;
#pragma unroll
    for (int j = 1; j < 16; j += 2) orv |= (unsigned)ei[j];
    return orv == 0u;  // 1 => int64 layout
}

__device__ inline void load_edge(const int* __restrict__ ei, int f, int e, int& s, int& d) {
    if (f) {  // int64: read 8B, use low word
        s = ((const int2*)ei)[e].x;
        d = ((const int2*)ei)[Ee + e].x;
    } else {
        s = ei[e];
        d = ei[Ee + e];
    }
}

// inclusive Hillis-Steele scan of n2 (<=512) ints with 256 threads, double-buffered.
__device__ inline int* scan_incl(int* pa, int* pb, int n2, int tid) {
    for (int off = 1; off < n2; off <<= 1) {
        for (int i = tid; i < n2; i += 256) pb[i] = pa[i] + ((i >= off) ? pa[i - off] : 0);
        __syncthreads();
        int* t = pa; pa = pb; pb = t;
    }
    return pa;
}

// ---------------- P1: binning scatter into FIXED-STRIDE arena (no pre-hist/scan) ----------------
// Bin b owns arena[b*SEGCAP .. ); per-chunk runs placed via atomicAdd(binCursor[b]).
__global__ __launch_bounds__(256) void bin_scatter(const int* __restrict__ ei,
                                                   int* __restrict__ binCursor,
                                                   unsigned* __restrict__ arena) {
    __shared__ unsigned srec[CHUNK];                       // 32 KB
    __shared__ int bcnt[BINS], bpfx[BINS], bfill[BINS], gbase[BINS];
    __shared__ int pA[512], pB[512];
    const int tid = threadIdx.x;
    const int e0 = blockIdx.x * CHUNK;
    const int n = min(CHUNK, Ee - e0);
    const int f = detect_flag(ei);

    for (int i = tid; i < BINS; i += 256) { bcnt[i] = 0; bfill[i] = 0; }
    __syncthreads();
    for (int i = tid; i < n; i += 256) {
        int s, d;
        load_edge(ei, f, e0 + i, s, d);
        if ((unsigned)s < (unsigned)Nn && (unsigned)d < (unsigned)Nn)
            atomicAdd(&bcnt[d >> BINSH], 1);
    }
    __syncthreads();
    for (int i = tid; i < 512; i += 256) pA[i] = (i < BINS) ? bcnt[i] : 0;
    __syncthreads();
    int* incl = scan_incl(pA, pB, 512, tid);
    for (int i = tid; i < BINS; i += 256) {
        bpfx[i] = incl[i] - bcnt[i];
        gbase[i] = bcnt[i] ? atomicAdd(&binCursor[i], bcnt[i]) : 0;
    }
    __syncthreads();
    for (int i = tid; i < n; i += 256) {
        int s, d;
        load_edge(ei, f, e0 + i, s, d);
        if ((unsigned)s < (unsigned)Nn && (unsigned)d < (unsigned)Nn) {
            int bin = d >> BINSH;
            int lp = atomicAdd(&bfill[bin], 1);
            srec[bpfx[bin] + lp] = ((unsigned)(d & (BINSZ - 1)) << 17) | (unsigned)s;
        }
    }
    __syncthreads();
    const int wid = tid >> 6, lane = tid & 63;
    for (int bin = wid; bin < BINS; bin += 4) {
        int cnt = bcnt[bin], off = bpfx[bin], gb = gbase[bin];
        for (int j = lane; j < cnt; j += 64)
            if (gb + j < SEGCAP) arena[(size_t)bin * SEGCAP + gb + j] = srec[off + j];
    }
}

// ---------------- P2: per-bin finalize -> PADDED CSR + per-node record ----------------
// rec[node] (48 B): {idx0..7 (first 8 padded srcs), basePad, deg, dinv_bits, 0}
__global__ __launch_bounds__(256) void bin_finalize(const int* __restrict__ binCursor,
                                                    const unsigned* __restrict__ arena,
                                                    float* __restrict__ dinv,
                                                    int* __restrict__ sortedSrc,
                                                    i32x4* __restrict__ rec) {
    __shared__ unsigned seg[SEGCAP];   // 21 KB
    __shared__ int ssrc[PADCAP];       // 28.7 KB
    __shared__ int cnt[BINSZ], fill[BINSZ], pA[BINSZ], pB[BINSZ];
    const int tid = threadIdx.x;
    const int b = blockIdx.x;
    int len = binCursor[b];
    if (len > SEGCAP) len = SEGCAP;

    for (int i = tid; i < len; i += 256) seg[i] = arena[(size_t)b * SEGCAP + i];
    for (int i = tid; i < BINSZ; i += 256) { cnt[i] = 0; fill[i] = 0; }
    __syncthreads();
    for (int i = tid; i < len; i += 256) atomicAdd(&cnt[seg[i] >> 17], 1);
    __syncthreads();
    for (int i = tid; i < BINSZ; i += 256) pA[i] = (cnt[i] + 7) & ~7;  // padded counts
    __syncthreads();
    int* incl = scan_incl(pA, pB, BINSZ, tid);

    const int node0 = b * BINSZ;
    const int padLen = incl[BINSZ - 1];
    for (int i = tid; i < padLen; i += 256) ssrc[i] = Nn;  // sentinel -> zero row
    __syncthreads();
    for (int i = tid; i < len; i += 256) {
        unsigned r = seg[i];
        int dl = r >> 17, s = (int)(r & 0x1FFFFu);
        int pc = (cnt[dl] + 7) & ~7;
        int p = atomicAdd(&fill[dl], 1);
        ssrc[incl[dl] - pc + p] = s;
    }
    __syncthreads();
    for (int t = tid; t < BINSZ; t += 256) {
        int node = node0 + t;
        if (node < Nn) {
            int c = cnt[t];
            int pc = (c + 7) & ~7;
            int start = incl[t] - pc;  // local
            float dv = rsqrtf((float)(c + 1));  // +1 self loop
            dinv[node] = dv;
            i32x4 r0, r1, r2;
#pragma unroll
            for (int j = 0; j < 4; ++j) r0[j] = (j < pc) ? ssrc[start + j] : Nn;
#pragma unroll
            for (int j = 0; j < 4; ++j) r1[j] = (4 + j < pc) ? ssrc[start + 4 + j] : Nn;
            r2[0] = b * PADCAP + start;
            r2[1] = c;
            r2[2] = __float_as_int(dv);
            r2[3] = 0;
            rec[(size_t)node * 3 + 0] = r0;
            rec[(size_t)node * 3 + 1] = r1;
            rec[(size_t)node * 3 + 2] = r2;
        }
    }
    __syncthreads();
    for (int i = tid; i < padLen; i += 256) sortedSrc[(size_t)b * PADCAP + i] = ssrc[i];
}

// ---------------- merged prep ----------------
// blocks 0-2: conv-W transposes; block 3: Wct + fp8 tmp sentinel row.
__global__ __launch_bounds__(256) void prep_all(const float* __restrict__ W0,
                                                const float* __restrict__ W1,
                                                const float* __restrict__ W2,
                                                const float* __restrict__ Wc,
                                                f16* __restrict__ WtAll,
                                                f16* __restrict__ Wct,
                                                unsigned char* __restrict__ tmp8) {
    int b = blockIdx.x;
    if (b < 3) {
        const float* W = (b == 0) ? W0 : ((b == 1) ? W1 : W2);
        f16* Wt = WtAll + (size_t)b * D * D;
        for (int i = threadIdx.x; i < D * D; i += 256) {
            int k = i >> 7, c = i & 127;
            Wt[c * D + k] = (f16)W[i];
        }
    } else {
        if (threadIdx.x < 32)  // fp8 sentinel zero row (128 B)
            ((unsigned*)(tmp8 + (size_t)Nn * 128))[threadIdx.x] = 0u;
        for (int i = threadIdx.x; i < CPAD * WS; i += 256) {
            int c = i / WS, k = i - c * WS;
            f16 v = (f16)0.0f;
            if (c < DOUT && k < DCAT) v = (f16)Wc[k * DOUT + c];
            Wct[i] = v;
        }
    }
}

// ---------------- fused embed+conv1 GEMM ----------------
// h0 = relu(x @ We^T + b_e) -> hcat part0 AND LDS (swizzled);
// tmp8 = fp8_e4m3( (h0 @ W1^T) * dinv ). Saves the 25.6 MB h0 re-read.
__global__ __launch_bounds__(256) void gemm_fused01(const float* __restrict__ x,
                                                    const f16* __restrict__ WeT,
                                                    const f16* __restrict__ W1T,
                                                    const float* __restrict__ b_embed,
                                                    const float* __restrict__ dinv,
                                                    f16* __restrict__ hcat,
                                                    unsigned char* __restrict__ tmp8) {
    __shared__ f16 Bsw[128 * 128];  // 32 KB (We^T, then W1^T)
    __shared__ f16 Hsw[128 * 128];  // 32 KB h0 tile
    const int tid = threadIdx.x;
    const int r0 = blockIdx.x * 128;
    const int lane = tid & 63;
    const int w = tid >> 6;
    const int wr = w * 32;

    {   // stage We^T
        int row = tid >> 1, half = (tid & 1) * 128;
#pragma unroll
        for (int i = 0; i < 8; ++i) {
            int bir = half + i * 16;
            uint4 v = *(const uint4*)((const char*)WeT + (size_t)row * 256 + bir);
            *(uint4*)((char*)Bsw + row * 256 + (bir ^ ((row & 7) << 4))) = v;
        }
    }
    __syncthreads();

    f32x4 acc[2][8];
#pragma unroll
    for (int mf = 0; mf < 2; ++mf)
#pragma unroll
        for (int nf = 0; nf < 8; ++nf) acc[mf][nf] = (f32x4){0, 0, 0, 0};

    // ---- GEMM0: A = x (fp32, direct from global) ----
#pragma unroll
    for (int kk = 0; kk < 4; ++kk) {
        const int ke = kk * 32 + (lane >> 4) * 8;
        f16x8 a[2], b[8];
#pragma unroll
        for (int mf = 0; mf < 2; ++mf) {
            int row = r0 + wr + mf * 16 + (lane & 15);
            int rc = (row < Nn) ? row : (Nn - 1);
            const float* p = x + (size_t)rc * D + ke;
            float4 f0 = *(const float4*)p;
            float4 f1 = *(const float4*)(p + 4);
            f16x8 h;
            h[0] = (f16)f0.x; h[1] = (f16)f0.y; h[2] = (f16)f0.z; h[3] = (f16)f0.w;
            h[4] = (f16)f1.x; h[5] = (f16)f1.y; h[6] = (f16)f1.z; h[7] = (f16)f1.w;
            a[mf] = h;
        }
#pragma unroll
        for (int nf = 0; nf < 8; ++nf) {
            int col = nf * 16 + (lane & 15);
            int bir = kk * 64 + (lane >> 4) * 16;
            b[nf] = *(const f16x8*)((const char*)Bsw + col * 256 + (bir ^ ((col & 7) << 4)));
        }
#pragma unroll
        for (int mf = 0; mf < 2; ++mf)
#pragma unroll
            for (int nf = 0; nf < 8; ++nf)
                acc[mf][nf] = __builtin_amdgcn_mfma_f32_16x16x32_f16(a[mf], b[nf], acc[mf][nf], 0, 0, 0);
    }

    // ---- epilogue0: bias+relu -> hcat part0 + Hsw (swizzled) ----
    {
        float bv[8];
#pragma unroll
        for (int nf = 0; nf < 8; ++nf) bv[nf] = b_embed[nf * 16 + (lane & 15)];
#pragma unroll
        for (int mf = 0; mf < 2; ++mf) {
#pragma unroll
            for (int i = 0; i < 4; ++i) {
                int lrow = wr + mf * 16 + (lane >> 4) * 4 + i;
                int row = r0 + lrow;
#pragma unroll
                for (int nf = 0; nf < 8; ++nf) {
                    float v = acc[mf][nf][i] + bv[nf];
                    if (v < 0.0f) v = 0.0f;
                    f16 hv = (f16)v;
                    if (row < Nn) hcat[(size_t)row * DCAT + nf * 16 + (lane & 15)] = hv;
                    int bir = (nf * 16 + (lane & 15)) * 2;
                    *(f16*)((char*)Hsw + lrow * 256 + (bir ^ ((lrow & 7) << 4))) = hv;
                }
            }
        }
    }
    __syncthreads();

    {   // restage W1^T
        int row = tid >> 1, half = (tid & 1) * 128;
#pragma unroll
        for (int i = 0; i < 8; ++i) {
            int bir = half + i * 16;
            uint4 v = *(const uint4*)((const char*)W1T + (size_t)row * 256 + bir);
            *(uint4*)((char*)Bsw + row * 256 + (bir ^ ((row & 7) << 4))) = v;
        }
    }
#pragma unroll
    for (int mf = 0; mf < 2; ++mf)
#pragma unroll
        for (int nf = 0; nf < 8; ++nf) acc[mf][nf] = (f32x4){0, 0, 0, 0};
    __syncthreads();

    // ---- GEMM1: A = h0 tile from Hsw ----
#pragma unroll
    for (int kk = 0; kk < 4; ++kk) {
        f16x8 a[2], b[8];
#pragma unroll
        for (int mf = 0; mf < 2; ++mf) {
            int lrow = wr + mf * 16 + (lane & 15);
            int bir = kk * 64 + (lane >> 4) * 16;
            a[mf] = *(const f16x8*)((const char*)Hsw + lrow * 256 + (bir ^ ((lrow & 7) << 4)));
        }
#pragma unroll
        for (int nf = 0; nf < 8; ++nf) {
            int col = nf * 16 + (lane & 15);
            int bir = kk * 64 + (lane >> 4) * 16;
            b[nf] = *(const f16x8*)((const char*)Bsw + col * 256 + (bir ^ ((col & 7) << 4)));
        }
#pragma unroll
        for (int mf = 0; mf < 2; ++mf)
#pragma unroll
            for (int nf = 0; nf < 8; ++nf)
                acc[mf][nf] = __builtin_amdgcn_mfma_f32_16x16x32_f16(a[mf], b[nf], acc[mf][nf], 0, 0, 0);
    }

    // ---- epilogue1: tmp8 = fp8(acc * dinv) ----
#pragma unroll
    for (int mf = 0; mf < 2; ++mf) {
#pragma unroll
        for (int i = 0; i < 4; ++i) {
            int row = r0 + wr + mf * 16 + (lane >> 4) * 4 + i;
            if (row < Nn) {
                float sc = dinv[row];
#pragma unroll
                for (int nf = 0; nf < 8; ++nf) {
                    float v = acc[mf][nf][i] * sc;
                    unsigned pk = __builtin_amdgcn_cvt_pk_fp8_f32(v, v, 0, false);
                    tmp8[(size_t)row * 128 + nf * 16 + (lane & 15)] = (unsigned char)pk;
                }
            }
        }
    }
}

// ---------------- MFMA GEMM (conv2): tmp8 = fp8((A @ Wt^T) * dinv) ----------------
__global__ __launch_bounds__(256) void gemm_mfma(const f16* __restrict__ Ain, int sA,
                                                 const f16* __restrict__ Wt,
                                                 const float* __restrict__ scale,
                                                 unsigned char* __restrict__ tmp8,
                                                 int M) {
    __shared__ f16 Bsw[128 * 128];  // 32 KB
    const int tid = threadIdx.x;
    const int r0 = blockIdx.x * 128;

    {   // stage B
        int row = tid >> 1, half = (tid & 1) * 128;
#pragma unroll
        for (int i = 0; i < 8; ++i) {
            int bir = half + i * 16;
            uint4 v = *(const uint4*)((const char*)Wt + (size_t)row * 256 + bir);
            *(uint4*)((char*)Bsw + row * 256 + (bir ^ ((row & 7) << 4))) = v;
        }
    }
    __syncthreads();

    const int lane = tid & 63;
    const int w    = tid >> 6;
    const int wr   = w * 32;

    f32x4 acc[2][8];
#pragma unroll
    for (int mf = 0; mf < 2; ++mf)
#pragma unroll
        for (int nf = 0; nf < 8; ++nf) acc[mf][nf] = (f32x4){0, 0, 0, 0};

#pragma unroll
    for (int kk = 0; kk < 4; ++kk) {
        const int ke = kk * 32 + (lane >> 4) * 8;
        f16x8 a[2], b[8];
#pragma unroll
        for (int mf = 0; mf < 2; ++mf) {
            int row = r0 + wr + mf * 16 + (lane & 15);
            int rc = (row < M) ? row : (M - 1);
            a[mf] = *(const f16x8*)(Ain + (size_t)rc * sA + ke);
        }
#pragma unroll
        for (int nf = 0; nf < 8; ++nf) {
            int col = nf * 16 + (lane & 15);
            int bir = kk * 64 + (lane >> 4) * 16;
            b[nf] = *(const f16x8*)((const char*)Bsw + col * 256 + (bir ^ ((col & 7) << 4)));
        }
#pragma unroll
        for (int mf = 0; mf < 2; ++mf)
#pragma unroll
            for (int nf = 0; nf < 8; ++nf)
                acc[mf][nf] = __builtin_amdgcn_mfma_f32_16x16x32_f16(a[mf], b[nf], acc[mf][nf], 0, 0, 0);
    }

#pragma unroll
    for (int mf = 0; mf < 2; ++mf) {
#pragma unroll
        for (int i = 0; i < 4; ++i) {
            int row = r0 + wr + mf * 16 + (lane >> 4) * 4 + i;
            if (row < M) {
                float sc = scale[row];
#pragma unroll
                for (int nf = 0; nf < 8; ++nf) {
                    float v = acc[mf][nf][i] * sc;
                    unsigned pk = __builtin_amdgcn_cvt_pk_fp8_f32(v, v, 0, false);
                    tmp8[(size_t)row * 128 + nf * 16 + (lane & 15)] = (unsigned char)pk;
                }
            }
        }
    }
}

// ---------------- aggregation: fp8 rows, dword/lane, record-fed first iteration ----------------
// rec[node] = {idx0..7, basePad, deg, dinv_bits, 0}: one coalesced 48B load replaces the
// meta->idx serial chain for iter 1; later iters' idx loads overlap iter-1 gathers.
__global__ __launch_bounds__(256) void aggregate_pad(const unsigned char* __restrict__ tmp8,
                                                     const i32x4* __restrict__ rec,
                                                     const int* __restrict__ sortedSrc,
                                                     const float* __restrict__ bias,
                                                     f16* __restrict__ hcat, int partOff) {
    int node = (blockIdx.x * 256 + threadIdx.x) >> 6;  // one wave per node
    int lane = threadIdx.x & 63;
    int l32  = lane & 31;   // dword index within row (features 4*l32..4*l32+3)
    int h    = lane >> 5;   // half-wave: edge-slot group
    if (node >= Nn) return;
    const unsigned* t4 = (const unsigned*)tmp8;  // row = 32 dwords (128 fp8)

    i32x4 rI = rec[(size_t)node * 3 + h];   // this half's first-4 indices
    i32x4 rM = rec[(size_t)node * 3 + 2];   // {basePad, deg, dinv_bits, 0}
    unsigned sv = t4[(size_t)node * 32 + l32];  // self (issues in parallel)

    int base = rM[0];
    int pc = (rM[1] + 7) & ~7;
    float di = __int_as_float(rM[2]);

    f32x2 aLo = (f32x2){0.0f, 0.0f};
    f32x2 aHi = (f32x2){0.0f, 0.0f};
    if (h == 0) {  // self loop counted once
        aLo = __builtin_amdgcn_cvt_pk_f32_fp8((int)sv, false);
        aHi = __builtin_amdgcn_cvt_pk_f32_fp8((int)sv, true);
    }

    {   // iter 1: gathers straight from the record (no idx-load dependency)
        unsigned g0 = t4[(size_t)rI[0] * 32 + l32];
        unsigned g1 = t4[(size_t)rI[1] * 32 + l32];
        unsigned g2 = t4[(size_t)rI[2] * 32 + l32];
        unsigned g3 = t4[(size_t)rI[3] * 32 + l32];
        aLo += __builtin_amdgcn_cvt_pk_f32_fp8((int)g0, false);
        aHi += __builtin_amdgcn_cvt_pk_f32_fp8((int)g0, true);
        aLo += __builtin_amdgcn_cvt_pk_f32_fp8((int)g1, false);
        aHi += __builtin_amdgcn_cvt_pk_f32_fp8((int)g1, true);
        aLo += __builtin_amdgcn_cvt_pk_f32_fp8((int)g2, false);
        aHi += __builtin_amdgcn_cvt_pk_f32_fp8((int)g2, true);
        aLo += __builtin_amdgcn_cvt_pk_f32_fp8((int)g3, false);
        aHi += __builtin_amdgcn_cvt_pk_f32_fp8((int)g3, true);
    }

    for (int e = 8; e < pc; e += 8) {
        i32x4 idx = *(const i32x4*)(sortedSrc + base + e + h * 4);
        unsigned g0 = t4[(size_t)idx[0] * 32 + l32];
        unsigned g1 = t4[(size_t)idx[1] * 32 + l32];
        unsigned g2 = t4[(size_t)idx[2] * 32 + l32];
        unsigned g3 = t4[(size_t)idx[3] * 32 + l32];
        aLo += __builtin_amdgcn_cvt_pk_f32_fp8((int)g0, false);
        aHi += __builtin_amdgcn_cvt_pk_f32_fp8((int)g0, true);
        aLo += __builtin_amdgcn_cvt_pk_f32_fp8((int)g1, false);
        aHi += __builtin_amdgcn_cvt_pk_f32_fp8((int)g1, true);
        aLo += __builtin_amdgcn_cvt_pk_f32_fp8((int)g2, false);
        aHi += __builtin_amdgcn_cvt_pk_f32_fp8((int)g2, true);
        aLo += __builtin_amdgcn_cvt_pk_f32_fp8((int)g3, false);
        aHi += __builtin_amdgcn_cvt_pk_f32_fp8((int)g3, true);
    }

    // cross-half reduce (features identical across halves)
    aLo[0] += __shfl_xor(aLo[0], 32);
    aLo[1] += __shfl_xor(aLo[1], 32);
    aHi[0] += __shfl_xor(aHi[0], 32);
    aHi[1] += __shfl_xor(aHi[1], 32);

    if (h == 0) {
        float4 bb = *(const float4*)(bias + l32 * 4);
        float o0 = di * aLo[0] + bb.x;
        float o1 = di * aLo[1] + bb.y;
        float o2 = di * aHi[0] + bb.z;
        float o3 = di * aHi[1] + bb.w;
        if (o0 < 0.0f) o0 = 0.0f;
        if (o1 < 0.0f) o1 = 0.0f;
        if (o2 < 0.0f) o2 = 0.0f;
        if (o3 < 0.0f) o3 = 0.0f;
        f16x4 o;
        o[0] = (f16)o0; o[1] = (f16)o1; o[2] = (f16)o2; o[3] = (f16)o3;
        *(f16x4*)(hcat + (size_t)node * DCAT + partOff + l32 * 4) = o;
    }
}

// ---------------- MFMA classifier: out[N,40] = hcat[N,384] @ Wct^T + b ----------------
__global__ __launch_bounds__(256) void cls_mfma(const f16* __restrict__ hcat,
                                                const f16* __restrict__ Wct,
                                                const float* __restrict__ bc,
                                                float* __restrict__ out) {
    __shared__ f16 Bs[CPAD * WS];  // 37.6 KB
    const int tid = threadIdx.x;
    for (int i = tid; i < CPAD * WS / 8; i += 256)
        ((uint4*)Bs)[i] = ((const uint4*)Wct)[i];
    __syncthreads();

    const int lane = tid & 63;
    const int w    = tid >> 6;
    const int r0   = blockIdx.x * 128 + w * 32;

    f32x4 acc[2][3];
#pragma unroll
    for (int mf = 0; mf < 2; ++mf)
#pragma unroll
        for (int nf = 0; nf < 3; ++nf) acc[mf][nf] = (f32x4){0, 0, 0, 0};

#pragma unroll 3
    for (int kk = 0; kk < 12; ++kk) {
        const int ke = kk * 32 + (lane >> 4) * 8;
        f16x8 a[2], b[3];
#pragma unroll
        for (int mf = 0; mf < 2; ++mf) {
            int row = r0 + mf * 16 + (lane & 15);
            int rc = (row < Nn) ? row : (Nn - 1);
            a[mf] = *(const f16x8*)(hcat + (size_t)rc * DCAT + ke);
        }
#pragma unroll
        for (int nf = 0; nf < 3; ++nf) {
            int col = nf * 16 + (lane & 15);
            b[nf] = *(const f16x8*)(Bs + col * WS + ke);
        }
#pragma unroll
        for (int mf = 0; mf < 2; ++mf)
#pragma unroll
            for (int nf = 0; nf < 3; ++nf)
                acc[mf][nf] = __builtin_amdgcn_mfma_f32_16x16x32_f16(a[mf], b[nf], acc[mf][nf], 0, 0, 0);
    }

    float bv[3];
#pragma unroll
    for (int nf = 0; nf < 3; ++nf) {
        int col = nf * 16 + (lane & 15);
        bv[nf] = (col < DOUT) ? bc[col] : 0.0f;
    }
#pragma unroll
    for (int mf = 0; mf < 2; ++mf) {
#pragma unroll
        for (int i = 0; i < 4; ++i) {
            int row = r0 + mf * 16 + (lane >> 4) * 4 + i;
            if (row < Nn) {
#pragma unroll
                for (int nf = 0; nf < 3; ++nf) {
                    int col = nf * 16 + (lane & 15);
                    if (col < DOUT) out[(size_t)row * DOUT + col] = acc[mf][nf][i] + bv[nf];
                }
            }
        }
    }
}

// ---------------- launch ----------------
extern "C" void kernel_launch(void* const* d_in, const int* in_sizes, int n_in,
                              void* d_out, int out_size, void* d_ws, size_t ws_size,
                              hipStream_t stream) {
    const float* x       = (const float*)d_in[0];
    const int*   ei      = (const int*)d_in[1];
    const float* W_embed = (const float*)d_in[2];
    const float* b_embed = (const float*)d_in[3];
    const float* W_conv1 = (const float*)d_in[4];
    const float* b_conv1 = (const float*)d_in[5];
    const float* W_conv2 = (const float*)d_in[6];
    const float* b_conv2 = (const float*)d_in[7];
    const float* W_cls   = (const float*)d_in[8];
    const float* b_cls   = (const float*)d_in[9];
    float* out = (float*)d_out;

    char* p = (char*)d_ws;
    size_t o = 0;
    auto carve = [&](size_t bytes) {
        char* r = p + o;
        o = (o + bytes + 255) & ~(size_t)255;
        return r;
    };
    int*      binCursor = (int*)carve((size_t)BINS * 4);
    int*      sortedSrc = (int*)carve(((size_t)BINS * PADCAP + 1024) * 4);  // 11.2 MB
    i32x4*    rec       = (i32x4*)carve((size_t)Nn * 48);                   // 4.8 MB
    float*    dinv      = (float*)carve((size_t)Nn * 4);
    f16*      WtAll     = (f16*)carve((size_t)3 * D * D * 2);
    f16*      Wct       = (f16*)carve((size_t)CPAD * WS * 2);
    f16*      hcat      = (f16*)carve((size_t)Nn * DCAT * 2);          // 76.8 MB
    unsigned char* tmp8 = (unsigned char*)carve((size_t)(Nn + 1) * 128);  // 12.8 MB fp8 (+sentinel)
    (void)ws_size;

    // liveness alias: arena (sort-only, 8.4 MB fixed-stride) overlays hcat
    unsigned* arena = (unsigned*)hcat;

    hipMemsetAsync(binCursor, 0, (size_t)BINS * 4, stream);
    bin_scatter<<<NCHUNK, 256, 0, stream>>>(ei, binCursor, arena);
    bin_finalize<<<BINS, 256, 0, stream>>>(binCursor, arena, dinv, sortedSrc, rec);
    prep_all<<<4, 256, 0, stream>>>(W_embed, W_conv1, W_conv2, W_cls, WtAll, Wct, tmp8);

    const int gGemm = (Nn + 127) / 128;
    const int gAgg  = (Nn * 64) / 256;

    // embed + conv1-GEMM fused: hcat part0 + tmp8 (fp8, *dinv)
    gemm_fused01<<<gGemm, 256, 0, stream>>>(x, WtAll, WtAll + D * D, b_embed, dinv, hcat, tmp8);
    // conv1 aggregate -> hcat part1
    aggregate_pad<<<gAgg, 256, 0, stream>>>(tmp8, rec, sortedSrc, b_conv1, hcat, D);
    // conv2: tmp8 = fp8((h1 @ W2)*dinv), aggregate -> hcat part2
    gemm_mfma<<<gGemm, 256, 0, stream>>>(hcat + D, DCAT, WtAll + 2 * D * D, dinv, tmp8, Nn);
    aggregate_pad<<<gAgg, 256, 0, stream>>>(tmp8, rec, sortedSrc, b_conv2, hcat, 2 * D);
    // classifier
    cls_mfma<<<gGemm, 256, 0, stream>>>(hcat, Wct, b_cls, out);
}